// Round 9
// baseline (1206.519 us; speedup 1.0000x reference)
//
#include <hip/hip_runtime.h>
#include <math.h>

typedef __attribute__((ext_vector_type(8))) short short8;
typedef __attribute__((ext_vector_type(4))) float floatx4;

static __device__ __forceinline__ short f2bf(float f) {
    union { float f; unsigned u; } c; c.f = f;
    unsigned r = c.u + 0x7FFF + ((c.u >> 16) & 1);   // RNE
    return (short)(r >> 16);
}

// ---------------------------------------------------------------------------
// fp32 GEMM: C[b] = alpha * A[b](M,K) x B[b](N,K)^T. 64x64 tile, 4x4 micro.
// Used only for read-phase attention logits (fp32 softmax path).
// ---------------------------------------------------------------------------
__launch_bounds__(256)
__global__ void gemm_f32_nt_kernel(const float* __restrict__ A, const float* __restrict__ B,
                                   float* __restrict__ C, int M, int N, int K,
                                   long sA, long sB, long sC, float alpha)
{
    __shared__ float As[32][68];   // [k][m]
    __shared__ float Bs[32][68];   // [k][n]
    const float* Ab = A + (long)blockIdx.z * sA;
    const float* Bb = B + (long)blockIdx.z * sB;
    float* Cb = C + (long)blockIdx.z * sC;
    int m0 = blockIdx.x * 64, n0 = blockIdx.y * 64;
    int t = threadIdx.x;
    int tx = t & 15, ty = t >> 4;
    float acc[4][4] = {};

    for (int k0 = 0; k0 < K; k0 += 32) {
        {
            int m = t >> 3;
            int kk = (t & 7) * 4;
#pragma unroll
            for (int h = 0; h < 2; ++h) {
                float4 v = *(const float4*)&Ab[(long)(m0 + m + 32 * h) * K + k0 + kk];
                As[kk + 0][m + 32 * h] = v.x; As[kk + 1][m + 32 * h] = v.y;
                As[kk + 2][m + 32 * h] = v.z; As[kk + 3][m + 32 * h] = v.w;
            }
        }
        {
            int n = t >> 3;
            int kk = (t & 7) * 4;
#pragma unroll
            for (int h = 0; h < 2; ++h) {
                float4 v = *(const float4*)&Bb[(long)(n0 + n + 32 * h) * K + k0 + kk];
                Bs[kk + 0][n + 32 * h] = v.x; Bs[kk + 1][n + 32 * h] = v.y;
                Bs[kk + 2][n + 32 * h] = v.z; Bs[kk + 3][n + 32 * h] = v.w;
            }
        }
        __syncthreads();
#pragma unroll 4
        for (int k = 0; k < 32; ++k) {
            float4 a = *(const float4*)&As[k][ty * 4];
            float4 b = *(const float4*)&Bs[k][tx * 4];
            float av[4] = { a.x, a.y, a.z, a.w };
            float bv[4] = { b.x, b.y, b.z, b.w };
#pragma unroll
            for (int i = 0; i < 4; ++i)
#pragma unroll
                for (int j = 0; j < 4; ++j) acc[i][j] += av[i] * bv[j];
        }
        __syncthreads();
    }
#pragma unroll
    for (int i = 0; i < 4; ++i) {
        float4 r;
        r.x = alpha * acc[i][0]; r.y = alpha * acc[i][1];
        r.z = alpha * acc[i][2]; r.w = alpha * acc[i][3];
        *(float4*)&Cb[(long)(m0 + ty * 4 + i) * N + n0 + tx * 4] = r;
    }
}

// ---------------------------------------------------------------------------
// Split-K q/k projection, fused (q and k in one launch), partials + reduce.
// ---------------------------------------------------------------------------
__launch_bounds__(256)
__global__ void proj_splitk_kernel(const float* __restrict__ Aq, const float* __restrict__ Ak,
                                   const float* __restrict__ Wq, const float* __restrict__ Wk,
                                   float* __restrict__ part,
                                   int Mq, int Mk, long sAq, long sAk, int Bn)
{
    __shared__ float As[32][68];
    __shared__ float Bs[32][68];
    int mqT = Mq >> 6;
    int xt = blockIdx.x, s = blockIdx.y, b = blockIdx.z;
    const float* A; const float* W; int row0, orow;
    if (xt < mqT) { A = Aq + (long)b * sAq; W = Wq; row0 = xt * 64; orow = row0; }
    else { A = Ak + (long)b * sAk; W = Wk; row0 = (xt - mqT) * 64; orow = Mq + row0; }
    int t = threadIdx.x, tx = t & 15, ty = t >> 4;
    float acc[4][4] = {};
    int kbase = s * 64;

    for (int k0 = kbase; k0 < kbase + 64; k0 += 32) {
        {
            int m = t >> 3;
            int kk = (t & 7) * 4;
#pragma unroll
            for (int h = 0; h < 2; ++h) {
                float4 v = *(const float4*)&A[(long)(row0 + m + 32 * h) * 512 + k0 + kk];
                As[kk + 0][m + 32 * h] = v.x; As[kk + 1][m + 32 * h] = v.y;
                As[kk + 2][m + 32 * h] = v.z; As[kk + 3][m + 32 * h] = v.w;
            }
        }
        {
            int kk = t >> 3;
            int nn = (t & 7) * 8;
            float4 v0 = *(const float4*)&W[(long)(k0 + kk) * 64 + nn];
            float4 v1 = *(const float4*)&W[(long)(k0 + kk) * 64 + nn + 4];
            *(float4*)&Bs[kk][nn] = v0;
            *(float4*)&Bs[kk][nn + 4] = v1;
        }
        __syncthreads();
#pragma unroll 4
        for (int k = 0; k < 32; ++k) {
            float4 a = *(const float4*)&As[k][ty * 4];
            float4 b2 = *(const float4*)&Bs[k][tx * 4];
            float av[4] = { a.x, a.y, a.z, a.w };
            float bv[4] = { b2.x, b2.y, b2.z, b2.w };
#pragma unroll
            for (int i = 0; i < 4; ++i)
#pragma unroll
                for (int j = 0; j < 4; ++j) acc[i][j] += av[i] * bv[j];
        }
        __syncthreads();
    }
    long base = ((long)(s * Bn + b) * (Mq + Mk) + orow) * 64;
#pragma unroll
    for (int i = 0; i < 4; ++i)
        *(float4*)&part[base + (long)(ty * 4 + i) * 64 + tx * 4] =
            make_float4(acc[i][0], acc[i][1], acc[i][2], acc[i][3]);
}

__launch_bounds__(256)
__global__ void proj_reduce_kernel(const float* __restrict__ part,
                                   float* __restrict__ qout, float* __restrict__ kout,
                                   int Mq, int Mk, int Bn)
{
    int idx = blockIdx.x * 256 + threadIdx.x;
    int size4b = (Mq + Mk) * 16;
    int total4 = Bn * size4b;
    if (idx >= total4) return;
    const float4* p4 = (const float4*)part;
    long stride4 = (long)total4;
    float4 s = p4[idx];
#pragma unroll
    for (int ss = 1; ss < 8; ++ss) {
        float4 v = p4[ss * stride4 + idx];
        s.x += v.x; s.y += v.y; s.z += v.z; s.w += v.w;
    }
    int b = idx / size4b;
    int rem = idx - b * size4b;
    int r = rem >> 4;
    int c4 = rem & 15;
    if (r < Mq) ((float4*)qout)[((long)b * Mq + r) * 16 + c4] = s;
    else        ((float4*)kout)[((long)b * Mk + (r - Mq)) * 16 + c4] = s;
}

// ---------------------------------------------------------------------------
// bf16 MFMA GEMM: C[b](M,N) = alpha' * A[b](M,K,fp32) x Bt[b](N,K,bf16) (+ C | + initC)
// ---------------------------------------------------------------------------
__launch_bounds__(256)
__global__ void gemm_mfma_kernel(const float* __restrict__ A, const unsigned short* __restrict__ Bt,
                                 float* __restrict__ C, int M, int N, int K,
                                 long sA, long sBt, long sC,
                                 float alpha, const float* __restrict__ gate, int gateIdx,
                                 float beta, const float* __restrict__ initC)
{
    __shared__ short As[2048];
    __shared__ short Bs[2048];
    const float* Ab = A + (long)blockIdx.z * sA;
    const unsigned short* Bb = Bt + (long)blockIdx.z * sBt;
    float* Cb = C + (long)blockIdx.z * sC;
    const float* Ib = initC ? initC + (long)blockIdx.z * sC : nullptr;
    int m0 = blockIdx.x * 64, n0 = blockIdx.y * 64;
    int t = threadIdx.x, wave = t >> 6, lane = t & 63;
    int sr = wave * 16 + (lane & 15);
    int sk = (lane >> 4) * 8;
    floatx4 acc[4] = {};

    for (int k0 = 0; k0 < K; k0 += 32) {
        const float* ap = &Ab[(long)(m0 + sr) * K + k0 + sk];
        float4 f0 = *(const float4*)ap;
        float4 f1 = *(const float4*)(ap + 4);
        short8 av;
        av[0] = f2bf(f0.x); av[1] = f2bf(f0.y); av[2] = f2bf(f0.z); av[3] = f2bf(f0.w);
        av[4] = f2bf(f1.x); av[5] = f2bf(f1.y); av[6] = f2bf(f1.z); av[7] = f2bf(f1.w);
        short8 bv = *(const short8*)&Bb[(long)(n0 + sr) * K + k0 + sk];
        ((short8*)As)[t] = av;
        ((short8*)Bs)[t] = bv;
        __syncthreads();
        short8 bf = ((short8*)Bs)[wave * 64 + lane];
#pragma unroll
        for (int mt = 0; mt < 4; ++mt) {
            short8 af = ((short8*)As)[mt * 64 + lane];
            acc[mt] = __builtin_amdgcn_mfma_f32_16x16x32_bf16(af, bf, acc[mt], 0, 0, 0);
        }
        __syncthreads();
    }
    float a = alpha;
    if (gate) a *= 1.f / (1.f + expf(-gate[gateIdx]));
    int col = n0 + wave * 16 + (lane & 15);
#pragma unroll
    for (int mt = 0; mt < 4; ++mt) {
#pragma unroll
        for (int r = 0; r < 4; ++r) {
            int row = m0 + mt * 16 + (lane >> 4) * 4 + r;
            long off = (long)row * N + col;
            float v = a * acc[mt][r];
            if (Ib) v += Ib[off];
            else if (beta != 0.f) v += Cb[off];
            Cb[off] = v;
        }
    }
}

// ---------------------------------------------------------------------------
// Transpose + bf16 convert: out[c][r] = bf16(in[r][c]).
// ---------------------------------------------------------------------------
__global__ void transpose_bf16_kernel(const float* __restrict__ in, unsigned short* __restrict__ out,
                                      int Rr, int Cc, long sIn, long sOut)
{
    __shared__ float tile[32][33];
    const float* I = in + (long)blockIdx.z * sIn;
    unsigned short* O = out + (long)blockIdx.z * sOut;
    int c0 = blockIdx.x * 32, r0 = blockIdx.y * 32;
    int tx = threadIdx.x, ty = threadIdx.y;
#pragma unroll
    for (int i = 0; i < 32; i += 8)
        tile[ty + i][tx] = I[(long)(r0 + ty + i) * Cc + c0 + tx];
    __syncthreads();
#pragma unroll
    for (int i = 0; i < 32; i += 8)
        O[(long)(c0 + ty + i) * Rr + r0 + tx] = (unsigned short)f2bf(tile[tx][ty + i]);
}

// ---------------------------------------------------------------------------
// FUSED logits + exact top-16 + CSR count. One wave per source row.
// logits[j] = dot(q_row, k_j) / 8 computed in-register (K=64); no lb matrix.
// Lane owns contiguous candidate slice [lane*CNT, lane*CNT+CNT).
// ---------------------------------------------------------------------------
template<int CNT>
__launch_bounds__(256)
__global__ void logits_topk_kernel(const float* __restrict__ q, const float* __restrict__ k,
                                   const float* __restrict__ state,
                                   int* __restrict__ idx_out, float* __restrict__ c_out,
                                   int* __restrict__ cnt, int nsLog, int Nd)
{
    int wave = threadIdx.x >> 6, lane = threadIdx.x & 63;
    long row = (long)blockIdx.x * 4 + wave;
    int b = (int)(row >> nsLog);
    const float* qr = q + row * 64;              // wave-uniform -> scalar loads
    const float* kbase = k + (long)b * Nd * 64;
    float4 q4[16];
#pragma unroll
    for (int i = 0; i < 16; ++i) q4[i] = *(const float4*)&qr[i * 4];

    float vreg[CNT];
#pragma unroll
    for (int tt = 0; tt < CNT; ++tt) {
        const float* kr = kbase + (long)(lane * CNT + tt) * 64;
        float s = 0.f;
#pragma unroll
        for (int i = 0; i < 16; ++i) {
            float4 kv = *(const float4*)&kr[i * 4];
            s += q4[i].x * kv.x + q4[i].y * kv.y + q4[i].z * kv.z + q4[i].w * kv.w;
        }
        vreg[tt] = s * 0.125f;
    }

    float m = 0.f, sum = 0.f;
    float myv = 0.f; int myi = 0;
#pragma unroll
    for (int it = 0; it < 16; ++it) {
        float best = -INFINITY; int bidx = 0x7fffffff;
#pragma unroll
        for (int tt = 0; tt < CNT; ++tt) {
            if (vreg[tt] > best) { best = vreg[tt]; bidx = lane * CNT + tt; }
        }
#pragma unroll
        for (int off = 32; off; off >>= 1) {
            float ov = __shfl_down(best, off);
            int   oi = __shfl_down(bidx, off);
            if (ov > best || (ov == best && oi < bidx)) { best = ov; bidx = oi; }
        }
        best = __shfl(best, 0);
        bidx = __shfl(bidx, 0);
        if (it == lane) { myv = best; myi = bidx; }
        float ab = fabsf(best);
        float nm = fmaxf(m, ab);
        sum = sum * expf(m - nm) + expf(ab - nm);
        m = nm;
#pragma unroll
        for (int tt = 0; tt < CNT; ++tt)
            if (lane * CNT + tt == bidx) vreg[tt] = -INFINITY;
    }
    if (lane < 16) {
        float st = state[row];
        float sp = fmaxf(st, 0.f) + log1pf(expf(-fabsf(st)));
        float sgn = (myv > 0.f) ? 1.f : ((myv < 0.f) ? -1.f : 0.f);
        float w = expf(fabsf(myv) - m) / sum;
        c_out[row * 16 + lane] = sgn * w * sp;
        idx_out[row * 16 + lane] = myi;
        atomicAdd(&cnt[b * Nd + myi], 1);
    }
}

// Single-block exclusive scan; self-zeroes cnt (next Nd <= current Nd).
__launch_bounds__(256)
__global__ void scan_kernel(int* __restrict__ cnt, int* __restrict__ offs, int N)
{
    __shared__ int sums[256];
    int t = threadIdx.x;
    int chunk = N >> 8;
    int base = t * chunk;
    int lc[16];
    int s = 0;
    for (int i = 0; i < chunk; ++i) { lc[i] = cnt[base + i]; s += lc[i]; }
    sums[t] = s;
    __syncthreads();
    for (int off = 1; off < 256; off <<= 1) {
        int v = (t >= off) ? sums[t - off] : 0;
        __syncthreads();
        sums[t] += v;
        __syncthreads();
    }
    int run = sums[t] - s;
    for (int i = 0; i < chunk; ++i) {
        offs[base + i] = run;
        run += lc[i];
        cnt[base + i] = 0;
    }
    if (t == 255) offs[N] = run;
}

__launch_bounds__(256)
__global__ void fill_edges_kernel(const int* __restrict__ idx, const int* __restrict__ offs,
                                  int* __restrict__ cursor, int* __restrict__ elist,
                                  int nsShift, int Nd, int E)
{
    int e = blockIdx.x * 256 + threadIdx.x;
    if (e >= E) return;
    int b = e >> nsShift;
    int d = b * Nd + idx[e];
    int pos = offs[d] + atomicAdd(&cursor[d], 1);
    elist[pos] = e;
}

// ---------------------------------------------------------------------------
// FUSED gather + LayerNorm: dv[row] accumulated in registers, then
// v_out[row] = LN(v_in[row] + gate*dv) * gamma + beta written directly.
// Also: ds[row] = sum c[e]; cursor[row] = 0 for next transition.
// v_out must not alias src_val (host ping-pongs buffers for prop transitions).
// ---------------------------------------------------------------------------
#define ECHUNK 512
__launch_bounds__(256)
__global__ void gather_ln_kernel(const float* __restrict__ src_val, const float* __restrict__ c,
                                 const int* __restrict__ elist, const int* __restrict__ offs,
                                 const float* __restrict__ v_in, float* __restrict__ v_out,
                                 float* __restrict__ ds, int* __restrict__ cursor,
                                 const float* __restrict__ gamma, const float* __restrict__ beta,
                                 const float* __restrict__ gatePtr, int gateIdx, int nsShift)
{
    __shared__ float sc[ECHUNK];
    __shared__ int   srow[ECHUNK];
    __shared__ float part[4][512];
    __shared__ float pcs[4];
    __shared__ float red[4];
    long row = blockIdx.x;
    int t = threadIdx.x, w = t >> 6, lane = t & 63;
    int e0 = offs[row], e1 = offs[row + 1];
    int mask = (1 << nsShift) - 1;
    int cb = lane * 8;
    float a[8] = {};
    float cs = 0.f;
    float gate = 1.f;
    if (gatePtr) gate = 1.f / (1.f + expf(-gatePtr[gateIdx]));

    for (int cstart = e0; cstart < e1; cstart += ECHUNK) {
        int cnt = min(e1 - cstart, ECHUNK);
        for (int i = t; i < cnt; i += 256) {
            int e = elist[cstart + i];
            sc[i] = c[e];
            int b = e >> nsShift;
            int s = (e & mask) >> 4;
            srow[i] = (b << (nsShift - 4)) + s;
        }
        __syncthreads();
        int j = w;
        for (; j + 12 < cnt; j += 16) {
            float c0 = sc[j], c1 = sc[j + 4], c2 = sc[j + 8], c3 = sc[j + 12];
            const float* p0 = src_val + ((long)srow[j]      << 9) + cb;
            const float* p1 = src_val + ((long)srow[j + 4]  << 9) + cb;
            const float* p2 = src_val + ((long)srow[j + 8]  << 9) + cb;
            const float* p3 = src_val + ((long)srow[j + 12] << 9) + cb;
            float4 x00 = *(const float4*)p0,       x01 = *(const float4*)(p0 + 4);
            float4 x10 = *(const float4*)p1,       x11 = *(const float4*)(p1 + 4);
            float4 x20 = *(const float4*)p2,       x21 = *(const float4*)(p2 + 4);
            float4 x30 = *(const float4*)p3,       x31 = *(const float4*)(p3 + 4);
            a[0] += c0 * x00.x + c1 * x10.x + c2 * x20.x + c3 * x30.x;
            a[1] += c0 * x00.y + c1 * x10.y + c2 * x20.y + c3 * x30.y;
            a[2] += c0 * x00.z + c1 * x10.z + c2 * x20.z + c3 * x30.z;
            a[3] += c0 * x00.w + c1 * x10.w + c2 * x20.w + c3 * x30.w;
            a[4] += c0 * x01.x + c1 * x11.x + c2 * x21.x + c3 * x31.x;
            a[5] += c0 * x01.y + c1 * x11.y + c2 * x21.y + c3 * x31.y;
            a[6] += c0 * x01.z + c1 * x11.z + c2 * x21.z + c3 * x31.z;
            a[7] += c0 * x01.w + c1 * x11.w + c2 * x21.w + c3 * x31.w;
            cs += c0 + c1 + c2 + c3;
        }
        for (; j < cnt; j += 4) {
            float cv = sc[j];
            const float* p = src_val + ((long)srow[j] << 9) + cb;
            float4 x0 = *(const float4*)p, x1 = *(const float4*)(p + 4);
            a[0] += cv * x0.x; a[1] += cv * x0.y; a[2] += cv * x0.z; a[3] += cv * x0.w;
            a[4] += cv * x1.x; a[5] += cv * x1.y; a[6] += cv * x1.z; a[7] += cv * x1.w;
            cs += cv;
        }
        __syncthreads();
    }
#pragma unroll
    for (int i = 0; i < 8; ++i) part[w][cb + i] = a[i];
    if (lane == 0) pcs[w] = cs;
    __syncthreads();
    float r0 = part[0][t] + part[1][t] + part[2][t] + part[3][t];
    float r1 = part[0][t + 256] + part[1][t + 256] + part[2][t + 256] + part[3][t + 256];
    if (t == 0) { ds[row] = pcs[0] + pcs[1] + pcs[2] + pcs[3]; cursor[row] = 0; }

    // ---- LayerNorm on x = v_in + gate*dv ----
    const float* vi = v_in + (row << 9);
    float x0 = vi[t]       + gate * r0;
    float x1 = vi[t + 256] + gate * r1;
    float s = x0 + x1;
    for (int off = 32; off; off >>= 1) s += __shfl_down(s, off);
    if ((t & 63) == 0) red[t >> 6] = s;
    __syncthreads();
    float mean = (red[0] + red[1] + red[2] + red[3]) * (1.f / 512.f);
    float d0 = x0 - mean, d1 = x1 - mean;
    float ss = d0 * d0 + d1 * d1;
    for (int off = 32; off; off >>= 1) ss += __shfl_down(ss, off);
    __syncthreads();
    if ((t & 63) == 0) red[t >> 6] = ss;
    __syncthreads();
    float var = (red[0] + red[1] + red[2] + red[3]) * (1.f / 512.f);
    float rstd = rsqrtf(var + 1e-5f);
    float* vo = v_out + (row << 9);
    vo[t]       = d0 * rstd * gamma[t]       + beta[t];
    vo[t + 256] = d1 * rstd * gamma[t + 256] + beta[t + 256];
}

// ---------------------------------------------------------------------------
// state' = sign(x)*softmax(|x|), x = s + gate*ds. One block per batch.
// ---------------------------------------------------------------------------
__launch_bounds__(256)
__global__ void apply_state_kernel(const float* __restrict__ s_in, const float* __restrict__ ds,
                                   float* __restrict__ s_out, int Nd,
                                   const float* __restrict__ gatePtr, int gateIdx)
{
    __shared__ float sh[1024];
    __shared__ float red[4];
    int b = blockIdx.x, t = threadIdx.x;
    float gate = 1.f;
    if (gatePtr) gate = 1.f / (1.f + expf(-gatePtr[gateIdx]));
    float lmax = 0.f;
    for (int i = t; i < Nd; i += 256) {
        float x = s_in[b * Nd + i] + gate * ds[b * Nd + i];
        sh[i] = x;
        lmax = fmaxf(lmax, fabsf(x));
    }
    for (int off = 32; off; off >>= 1) lmax = fmaxf(lmax, __shfl_down(lmax, off));
    if ((t & 63) == 0) red[t >> 6] = lmax;
    __syncthreads();
    float bmax = fmaxf(fmaxf(red[0], red[1]), fmaxf(red[2], red[3]));
    float lsum = 0.f;
    for (int i = t; i < Nd; i += 256) lsum += expf(fabsf(sh[i]) - bmax);
    for (int off = 32; off; off >>= 1) lsum += __shfl_down(lsum, off);
    __syncthreads();
    if ((t & 63) == 0) red[t >> 6] = lsum;
    __syncthreads();
    float inv = 1.f / (red[0] + red[1] + red[2] + red[3]);
    for (int i = t; i < Nd; i += 256) {
        float x = sh[i];
        float sgn = (x > 0.f) ? 1.f : ((x < 0.f) ? -1.f : 0.f);
        s_out[b * Nd + i] = sgn * expf(fabsf(x) - bmax) * inv;
    }
}

// ---------------------------------------------------------------------------
// Plain softmax over rows, in place (read phase).
// ---------------------------------------------------------------------------
__launch_bounds__(256)
__global__ void softmax_rows_kernel(float* __restrict__ logits, int Nd)
{
    __shared__ float red[4];
    long row = blockIdx.x;
    int t = threadIdx.x;
    float* L = logits + row * (long)Nd;
    float lmax = -INFINITY;
    for (int i = t; i < Nd; i += 256) lmax = fmaxf(lmax, L[i]);
    for (int off = 32; off; off >>= 1) lmax = fmaxf(lmax, __shfl_down(lmax, off));
    if ((t & 63) == 0) red[t >> 6] = lmax;
    __syncthreads();
    float bmax = fmaxf(fmaxf(red[0], red[1]), fmaxf(red[2], red[3]));
    float lsum = 0.f;
    for (int i = t; i < Nd; i += 256) lsum += expf(L[i] - bmax);
    for (int off = 32; off; off >>= 1) lsum += __shfl_down(lsum, off);
    __syncthreads();
    if ((t & 63) == 0) red[t >> 6] = lsum;
    __syncthreads();
    float inv = 1.f / (red[0] + red[1] + red[2] + red[3]);
    for (int i = t; i < Nd; i += 256) L[i] = expf(L[i] - bmax) * inv;
}

// ---------------------------------------------------------------------------
extern "C" void kernel_launch(void* const* d_in, const int* in_sizes, int n_in,
                              void* d_out, int out_size, void* d_ws, size_t ws_size,
                              hipStream_t stream)
{
    const int Bn = 4, T = 1024, D = 512, R = 64;
    const int S0 = 1024, S1 = 256, S2 = 64;
    const long RT = (long)D * R;

    const float* tok_val    = (const float*)d_in[0];
    const float* tok_state  = (const float*)d_in[1];
    const float* mem_state0 = (const float*)d_in[2];
    const float* mem_val0   = (const float*)d_in[3];
    const float* mem_state1 = (const float*)d_in[4];
    const float* mem_val1   = (const float*)d_in[5];
    const float* mem_state2 = (const float*)d_in[6];
    const float* mem_val2   = (const float*)d_in[7];
    const float* write_route= (const float*)d_in[8];
    const float* prop_route = (const float*)d_in[9];
    const float* level_route= (const float*)d_in[10];
    const float* skip_route = (const float*)d_in[11];
    const float* skip_gates = (const float*)d_in[12];
    const float* ln_gamma   = (const float*)d_in[13];
    const float* ln_beta    = (const float*)d_in[14];
    const float* read_route = (const float*)d_in[15];
    const float* read_proj  = (const float*)d_in[16];
    const float* read_gates = (const float*)d_in[17];
    float* out = (float*)d_out;

    // workspace carve
    float* p = (float*)d_ws;
    float* v0  = p; p += (long)Bn * S0 * D;
    float* v0b = p; p += (long)Bn * S0 * D;
    float* s0  = p; p += Bn * S0;
    float* v1  = p; p += (long)Bn * S1 * D;
    float* v1b = p; p += (long)Bn * S1 * D;
    float* s1  = p; p += Bn * S1;
    float* v2  = p; p += (long)Bn * S2 * D;
    float* v2b = p; p += (long)Bn * S2 * D;
    float* s2  = p; p += Bn * S2;
    float* qb  = p; p += (long)Bn * T * R;
    float* kb  = p; p += (long)Bn * S0 * R;
    float* lb  = p; p += (long)Bn * T * S0;      // read-phase attention only
    float* cbuf= p; p += (long)Bn * T * 16;
    int*   ib  = (int*)p; p += (long)Bn * T * 16;
    float* dsb = p; p += Bn * S0;
    float* rb  = p; p += (long)Bn * T * D;
    int* cntb  = (int*)p; p += Bn * S0;
    int* curb  = (int*)p; p += Bn * S0;
    int* offsb = (int*)p; p += Bn * S0 + 1;
    int* elistb= (int*)p; p += (long)Bn * T * 16;
    unsigned short* projT = (unsigned short*)p; p += (3 * (long)D * D) / 2 + 4;
    unsigned short* mvT   = (unsigned short*)p; p += ((long)Bn * D * S0) / 2 + 4;
    float* partb = p; p += 8L * Bn * (T + S0) * R;   // split-K partials

    auto proj = [&](const float* Aq, const float* Ak, const float* Wq, const float* Wk,
                    int Mq, int Mk, long sAq, long sAk, float* qout, float* kout) {
        proj_splitk_kernel<<<dim3((Mq + Mk) / 64, 8, Bn), 256, 0, stream>>>(
            Aq, Ak, Wq, Wk, partb, Mq, Mk, sAq, sAk, Bn);
        int total4 = Bn * (Mq + Mk) * 16;
        proj_reduce_kernel<<<(total4 + 255) / 256, 256, 0, stream>>>(
            partb, qout, kout, Mq, Mk, Bn);
    };

    // one-time zero of cnt + cursor (workspace is re-poisoned before every call)
    hipMemsetAsync(cntb, 0, (size_t)2 * Bn * S0 * sizeof(int), stream);

    // One transition: sv/ss = source val/state, dval = routing destination val,
    // v_in/v_out = value buffers for the LN update (v_out must not alias sv),
    // sin/sout = state buffers.
    auto trans = [&](const float* sv, const float* ss, const float* dval,
                     const float* W, int Ns, int Nd,
                     const float* v_in, float* v_out, const float* sin, float* sout,
                     int lvl, const float* gptr, int gidx) {
        proj(sv, dval, W, W + RT, Ns, Nd, (long)Ns * D, (long)Nd * D, qb, kb);
        int nsLog = 31 - __builtin_clz((unsigned)Ns);
        int nsShift = nsLog + 4;
        int rowBlocks = Bn * Ns / 4;
        if (Nd == 1024)
            logits_topk_kernel<16><<<rowBlocks, 256, 0, stream>>>(qb, kb, ss, ib, cbuf, cntb, nsLog, Nd);
        else if (Nd == 256)
            logits_topk_kernel<4><<<rowBlocks, 256, 0, stream>>>(qb, kb, ss, ib, cbuf, cntb, nsLog, Nd);
        else
            logits_topk_kernel<1><<<rowBlocks, 256, 0, stream>>>(qb, kb, ss, ib, cbuf, cntb, nsLog, Nd);
        int E = Bn * Ns * 16;
        scan_kernel<<<1, 256, 0, stream>>>(cntb, offsb, Bn * Nd);
        fill_edges_kernel<<<(E + 255) / 256, 256, 0, stream>>>(ib, offsb, curb, elistb,
                                                               nsShift, Nd, E);
        gather_ln_kernel<<<Bn * Nd, 256, 0, stream>>>(sv, cbuf, elistb, offsb,
                                                      v_in, v_out, dsb, curb,
                                                      ln_gamma + lvl * D, ln_beta + lvl * D,
                                                      gptr, gidx, nsShift);
        apply_state_kernel<<<Bn, 256, 0, stream>>>(sin, dsb, sout, Nd, gptr, gidx);
    };

    // ---- level 0 ----
    trans(tok_val, tok_state, mem_val0, write_route, T, S0,
          mem_val0, v0, mem_state0, s0, 0, nullptr, 0);
    trans(v0, s0, v0, prop_route + 0 * 2 * RT, S0, S0,
          v0, v0b, s0, s0, 0, nullptr, 0);                    // ping-pong: out = v0b

    // ---- level 1 ----
    trans(v0b, s0, mem_val1, level_route + 0 * 2 * RT, S0, S1,
          mem_val1, v1, mem_state1, s1, 1, nullptr, 0);
    trans(tok_val, tok_state, v1, skip_route + 0 * 2 * RT, T, S1,
          v1, v1, s1, s1, 1, skip_gates, 0);                  // in-place ok (sv=tok_val)
    trans(v1, s1, v1, prop_route + 1 * 2 * RT, S1, S1,
          v1, v1b, s1, s1, 1, nullptr, 0);                    // out = v1b

    // ---- level 2 ----
    trans(v1b, s1, mem_val2, level_route + 1 * 2 * RT, S1, S2,
          mem_val2, v2, mem_state2, s2, 2, nullptr, 0);
    trans(v0b, s0, v2, skip_route + 1 * 2 * RT, S0, S2,
          v2, v2, s2, s2, 2, skip_gates, 1);                  // in-place ok (sv=v0b)
    trans(v2, s2, v2, prop_route + 2 * 2 * RT, S2, S2,
          v2, v2b, s2, s2, 2, nullptr, 0);                    // out = v2b

    // ---- read phase ----
    transpose_bf16_kernel<<<dim3(D / 32, D / 32, 3), dim3(32, 8), 0, stream>>>(
        read_proj, projT, D, D, (long)D * D, (long)D * D);
    const float* mvs[3] = { v0b, v1b, v2b };
    const int nds[3] = { S0, S1, S2 };
    for (int l = 0; l < 3; ++l) {
        const float* mv = mvs[l];
        int Nd = nds[l];
        proj(tok_val, mv, read_route + (long)l * 2 * RT, read_route + (long)l * 2 * RT + RT,
             T, Nd, (long)T * D, (long)Nd * D, qb, kb);
        gemm_f32_nt_kernel<<<dim3(T / 64, Nd / 64, Bn), 256, 0, stream>>>(
            qb, kb, lb, T, Nd, R, (long)T * R, (long)Nd * R, (long)T * Nd, 0.125f);
        softmax_rows_kernel<<<Bn * T, 256, 0, stream>>>(lb, Nd);
        transpose_bf16_kernel<<<dim3(D / 32, Nd / 32, Bn), dim3(32, 8), 0, stream>>>(
            mv, mvT, Nd, D, (long)Nd * D, (long)D * Nd);
        gemm_mfma_kernel<<<dim3(T / 64, D / 64, Bn), 256, 0, stream>>>(
            lb, mvT, rb, T, D, Nd, (long)T * Nd, (long)D * Nd, (long)T * D,
            1.f, nullptr, 0, 0.f, nullptr);
        // out = (l==0 ? tok_val : out) + sigmoid(gate_l) * r x proj_l
        gemm_mfma_kernel<<<dim3(T / 64, D / 64, Bn), 256, 0, stream>>>(
            rb, projT + (long)l * D * D, out, T, D, D,
            (long)T * D, 0, (long)T * D, 1.f, read_gates, l,
            1.f, (l == 0) ? tok_val : nullptr);
    }
}

// Round 10
// 925.008 us; speedup vs baseline: 1.3043x; 1.3043x over previous
//
#include <hip/hip_runtime.h>
#include <math.h>

typedef __attribute__((ext_vector_type(8))) short short8;
typedef __attribute__((ext_vector_type(4))) float floatx4;

static __device__ __forceinline__ short f2bf(float f) {
    union { float f; unsigned u; } c; c.f = f;
    unsigned r = c.u + 0x7FFF + ((c.u >> 16) & 1);   // RNE
    return (short)(r >> 16);
}

// ---------------------------------------------------------------------------
// fp32 GEMM: C[b] = alpha * A[b](M,K) x B[b](N,K)^T. 64x64 tile, 4x4 micro.
// fp32-exact path (logits feed exact top-k; read-phase attention logits).
// ---------------------------------------------------------------------------
__launch_bounds__(256)
__global__ void gemm_f32_nt_kernel(const float* __restrict__ A, const float* __restrict__ B,
                                   float* __restrict__ C, int M, int N, int K,
                                   long sA, long sB, long sC, float alpha)
{
    __shared__ float As[32][68];   // [k][m]
    __shared__ float Bs[32][68];   // [k][n]
    const float* Ab = A + (long)blockIdx.z * sA;
    const float* Bb = B + (long)blockIdx.z * sB;
    float* Cb = C + (long)blockIdx.z * sC;
    int m0 = blockIdx.x * 64, n0 = blockIdx.y * 64;
    int t = threadIdx.x;
    int tx = t & 15, ty = t >> 4;
    float acc[4][4] = {};

    for (int k0 = 0; k0 < K; k0 += 32) {
        {
            int m = t >> 3;
            int kk = (t & 7) * 4;
#pragma unroll
            for (int h = 0; h < 2; ++h) {
                float4 v = *(const float4*)&Ab[(long)(m0 + m + 32 * h) * K + k0 + kk];
                As[kk + 0][m + 32 * h] = v.x; As[kk + 1][m + 32 * h] = v.y;
                As[kk + 2][m + 32 * h] = v.z; As[kk + 3][m + 32 * h] = v.w;
            }
        }
        {
            int n = t >> 3;
            int kk = (t & 7) * 4;
#pragma unroll
            for (int h = 0; h < 2; ++h) {
                float4 v = *(const float4*)&Bb[(long)(n0 + n + 32 * h) * K + k0 + kk];
                Bs[kk + 0][n + 32 * h] = v.x; Bs[kk + 1][n + 32 * h] = v.y;
                Bs[kk + 2][n + 32 * h] = v.z; Bs[kk + 3][n + 32 * h] = v.w;
            }
        }
        __syncthreads();
#pragma unroll 4
        for (int k = 0; k < 32; ++k) {
            float4 a = *(const float4*)&As[k][ty * 4];
            float4 b = *(const float4*)&Bs[k][tx * 4];
            float av[4] = { a.x, a.y, a.z, a.w };
            float bv[4] = { b.x, b.y, b.z, b.w };
#pragma unroll
            for (int i = 0; i < 4; ++i)
#pragma unroll
                for (int j = 0; j < 4; ++j) acc[i][j] += av[i] * bv[j];
        }
        __syncthreads();
    }
#pragma unroll
    for (int i = 0; i < 4; ++i) {
        float4 r;
        r.x = alpha * acc[i][0]; r.y = alpha * acc[i][1];
        r.z = alpha * acc[i][2]; r.w = alpha * acc[i][3];
        *(float4*)&Cb[(long)(m0 + ty * 4 + i) * N + n0 + tx * 4] = r;
    }
}

// ---------------------------------------------------------------------------
// Split-K q/k projection, fused (q and k in one launch), partials + reduce.
// ---------------------------------------------------------------------------
__launch_bounds__(256)
__global__ void proj_splitk_kernel(const float* __restrict__ Aq, const float* __restrict__ Ak,
                                   const float* __restrict__ Wq, const float* __restrict__ Wk,
                                   float* __restrict__ part,
                                   int Mq, int Mk, long sAq, long sAk, int Bn)
{
    __shared__ float As[32][68];
    __shared__ float Bs[32][68];
    int mqT = Mq >> 6;
    int xt = blockIdx.x, s = blockIdx.y, b = blockIdx.z;
    const float* A; const float* W; int row0, orow;
    if (xt < mqT) { A = Aq + (long)b * sAq; W = Wq; row0 = xt * 64; orow = row0; }
    else { A = Ak + (long)b * sAk; W = Wk; row0 = (xt - mqT) * 64; orow = Mq + row0; }
    int t = threadIdx.x, tx = t & 15, ty = t >> 4;
    float acc[4][4] = {};
    int kbase = s * 64;

    for (int k0 = kbase; k0 < kbase + 64; k0 += 32) {
        {
            int m = t >> 3;
            int kk = (t & 7) * 4;
#pragma unroll
            for (int h = 0; h < 2; ++h) {
                float4 v = *(const float4*)&A[(long)(row0 + m + 32 * h) * 512 + k0 + kk];
                As[kk + 0][m + 32 * h] = v.x; As[kk + 1][m + 32 * h] = v.y;
                As[kk + 2][m + 32 * h] = v.z; As[kk + 3][m + 32 * h] = v.w;
            }
        }
        {
            int kk = t >> 3;
            int nn = (t & 7) * 8;
            float4 v0 = *(const float4*)&W[(long)(k0 + kk) * 64 + nn];
            float4 v1 = *(const float4*)&W[(long)(k0 + kk) * 64 + nn + 4];
            *(float4*)&Bs[kk][nn] = v0;
            *(float4*)&Bs[kk][nn + 4] = v1;
        }
        __syncthreads();
#pragma unroll 4
        for (int k = 0; k < 32; ++k) {
            float4 a = *(const float4*)&As[k][ty * 4];
            float4 b2 = *(const float4*)&Bs[k][tx * 4];
            float av[4] = { a.x, a.y, a.z, a.w };
            float bv[4] = { b2.x, b2.y, b2.z, b2.w };
#pragma unroll
            for (int i = 0; i < 4; ++i)
#pragma unroll
                for (int j = 0; j < 4; ++j) acc[i][j] += av[i] * bv[j];
        }
        __syncthreads();
    }
    long base = ((long)(s * Bn + b) * (Mq + Mk) + orow) * 64;
#pragma unroll
    for (int i = 0; i < 4; ++i)
        *(float4*)&part[base + (long)(ty * 4 + i) * 64 + tx * 4] =
            make_float4(acc[i][0], acc[i][1], acc[i][2], acc[i][3]);
}

__launch_bounds__(256)
__global__ void proj_reduce_kernel(const float* __restrict__ part,
                                   float* __restrict__ qout, float* __restrict__ kout,
                                   int Mq, int Mk, int Bn)
{
    int idx = blockIdx.x * 256 + threadIdx.x;
    int size4b = (Mq + Mk) * 16;
    int total4 = Bn * size4b;
    if (idx >= total4) return;
    const float4* p4 = (const float4*)part;
    long stride4 = (long)total4;
    float4 s = p4[idx];
#pragma unroll
    for (int ss = 1; ss < 8; ++ss) {
        float4 v = p4[ss * stride4 + idx];
        s.x += v.x; s.y += v.y; s.z += v.z; s.w += v.w;
    }
    int b = idx / size4b;
    int rem = idx - b * size4b;
    int r = rem >> 4;
    int c4 = rem & 15;
    if (r < Mq) ((float4*)qout)[((long)b * Mq + r) * 16 + c4] = s;
    else        ((float4*)kout)[((long)b * Mk + (r - Mq)) * 16 + c4] = s;
}

// ---------------------------------------------------------------------------
// bf16 MFMA GEMM: C[b](M,N) = alpha' * A[b](M,K,fp32) x Bt[b](N,K,bf16) (+ C | + initC)
// ---------------------------------------------------------------------------
__launch_bounds__(256)
__global__ void gemm_mfma_kernel(const float* __restrict__ A, const unsigned short* __restrict__ Bt,
                                 float* __restrict__ C, int M, int N, int K,
                                 long sA, long sBt, long sC,
                                 float alpha, const float* __restrict__ gate, int gateIdx,
                                 float beta, const float* __restrict__ initC)
{
    __shared__ short As[2048];
    __shared__ short Bs[2048];
    const float* Ab = A + (long)blockIdx.z * sA;
    const unsigned short* Bb = Bt + (long)blockIdx.z * sBt;
    float* Cb = C + (long)blockIdx.z * sC;
    const float* Ib = initC ? initC + (long)blockIdx.z * sC : nullptr;
    int m0 = blockIdx.x * 64, n0 = blockIdx.y * 64;
    int t = threadIdx.x, wave = t >> 6, lane = t & 63;
    int sr = wave * 16 + (lane & 15);
    int sk = (lane >> 4) * 8;
    floatx4 acc[4] = {};

    for (int k0 = 0; k0 < K; k0 += 32) {
        const float* ap = &Ab[(long)(m0 + sr) * K + k0 + sk];
        float4 f0 = *(const float4*)ap;
        float4 f1 = *(const float4*)(ap + 4);
        short8 av;
        av[0] = f2bf(f0.x); av[1] = f2bf(f0.y); av[2] = f2bf(f0.z); av[3] = f2bf(f0.w);
        av[4] = f2bf(f1.x); av[5] = f2bf(f1.y); av[6] = f2bf(f1.z); av[7] = f2bf(f1.w);
        short8 bv = *(const short8*)&Bb[(long)(n0 + sr) * K + k0 + sk];
        ((short8*)As)[t] = av;
        ((short8*)Bs)[t] = bv;
        __syncthreads();
        short8 bf = ((short8*)Bs)[wave * 64 + lane];
#pragma unroll
        for (int mt = 0; mt < 4; ++mt) {
            short8 af = ((short8*)As)[mt * 64 + lane];
            acc[mt] = __builtin_amdgcn_mfma_f32_16x16x32_bf16(af, bf, acc[mt], 0, 0, 0);
        }
        __syncthreads();
    }
    float a = alpha;
    if (gate) a *= 1.f / (1.f + expf(-gate[gateIdx]));
    int col = n0 + wave * 16 + (lane & 15);
#pragma unroll
    for (int mt = 0; mt < 4; ++mt) {
#pragma unroll
        for (int r = 0; r < 4; ++r) {
            int row = m0 + mt * 16 + (lane >> 4) * 4 + r;
            long off = (long)row * N + col;
            float v = a * acc[mt][r];
            if (Ib) v += Ib[off];
            else if (beta != 0.f) v += Cb[off];
            Cb[off] = v;
        }
    }
}

// ---------------------------------------------------------------------------
// Transpose + bf16 convert: out[c][r] = bf16(in[r][c]).
// ---------------------------------------------------------------------------
__global__ void transpose_bf16_kernel(const float* __restrict__ in, unsigned short* __restrict__ out,
                                      int Rr, int Cc, long sIn, long sOut)
{
    __shared__ float tile[32][33];
    const float* I = in + (long)blockIdx.z * sIn;
    unsigned short* O = out + (long)blockIdx.z * sOut;
    int c0 = blockIdx.x * 32, r0 = blockIdx.y * 32;
    int tx = threadIdx.x, ty = threadIdx.y;
#pragma unroll
    for (int i = 0; i < 32; i += 8)
        tile[ty + i][tx] = I[(long)(r0 + ty + i) * Cc + c0 + tx];
    __syncthreads();
#pragma unroll
    for (int i = 0; i < 32; i += 8)
        O[(long)(c0 + ty + i) * Rr + r0 + tx] = (unsigned short)f2bf(tile[tx][ty + i]);
}

// ---------------------------------------------------------------------------
// Exact top-16 per row + fused CSR count. 4 rows/block (one wave per row),
// lane owns contiguous slice of the logits row (float4 loads from lb).
// ---------------------------------------------------------------------------
template<int CNT>
__launch_bounds__(256)
__global__ void topk_coeff_kernel(const float* __restrict__ logits,
                                  const float* __restrict__ state,
                                  int* __restrict__ idx_out, float* __restrict__ c_out,
                                  int* __restrict__ cnt, int nsLog, int Nd)
{
    int wave = threadIdx.x >> 6, lane = threadIdx.x & 63;
    long row = (long)blockIdx.x * 4 + wave;
    const float* L = logits + row * Nd;
    float vreg[CNT];
    if (CNT >= 4) {
#pragma unroll
        for (int q = 0; q < CNT / 4; ++q) {
            float4 v = *(const float4*)&L[lane * CNT + q * 4];
            vreg[q * 4 + 0] = v.x; vreg[q * 4 + 1] = v.y;
            vreg[q * 4 + 2] = v.z; vreg[q * 4 + 3] = v.w;
        }
    } else {
#pragma unroll
        for (int tt = 0; tt < CNT; ++tt) vreg[tt] = L[lane * CNT + tt];
    }

    float m = 0.f, sum = 0.f;
    float myv = 0.f; int myi = 0;
#pragma unroll
    for (int it = 0; it < 16; ++it) {
        float best = -INFINITY; int bidx = 0x7fffffff;
#pragma unroll
        for (int tt = 0; tt < CNT; ++tt) {
            if (vreg[tt] > best) { best = vreg[tt]; bidx = lane * CNT + tt; }
        }
#pragma unroll
        for (int off = 32; off; off >>= 1) {
            float ov = __shfl_down(best, off);
            int   oi = __shfl_down(bidx, off);
            if (ov > best || (ov == best && oi < bidx)) { best = ov; bidx = oi; }
        }
        best = __shfl(best, 0);
        bidx = __shfl(bidx, 0);
        if (it == lane) { myv = best; myi = bidx; }
        float ab = fabsf(best);
        float nm = fmaxf(m, ab);
        sum = sum * expf(m - nm) + expf(ab - nm);
        m = nm;
#pragma unroll
        for (int tt = 0; tt < CNT; ++tt)
            if (lane * CNT + tt == bidx) vreg[tt] = -INFINITY;
    }
    if (lane < 16) {
        float st = state[row];
        float sp = fmaxf(st, 0.f) + log1pf(expf(-fabsf(st)));
        float sgn = (myv > 0.f) ? 1.f : ((myv < 0.f) ? -1.f : 0.f);
        float w = expf(fabsf(myv) - m) / sum;
        c_out[row * 16 + lane] = sgn * w * sp;
        idx_out[row * 16 + lane] = myi;
        int b = (int)(row >> nsLog);
        atomicAdd(&cnt[b * Nd + myi], 1);
    }
}

// Single-block exclusive scan; self-zeroes cnt (next Nd <= current Nd).
__launch_bounds__(256)
__global__ void scan_kernel(int* __restrict__ cnt, int* __restrict__ offs, int N)
{
    __shared__ int sums[256];
    int t = threadIdx.x;
    int chunk = N >> 8;
    int base = t * chunk;
    int lc[16];
    int s = 0;
    for (int i = 0; i < chunk; ++i) { lc[i] = cnt[base + i]; s += lc[i]; }
    sums[t] = s;
    __syncthreads();
    for (int off = 1; off < 256; off <<= 1) {
        int v = (t >= off) ? sums[t - off] : 0;
        __syncthreads();
        sums[t] += v;
        __syncthreads();
    }
    int run = sums[t] - s;
    for (int i = 0; i < chunk; ++i) {
        offs[base + i] = run;
        run += lc[i];
        cnt[base + i] = 0;
    }
    if (t == 255) offs[N] = run;
}

__launch_bounds__(256)
__global__ void fill_edges_kernel(const int* __restrict__ idx, const int* __restrict__ offs,
                                  int* __restrict__ cursor, int* __restrict__ elist,
                                  int nsShift, int Nd, int E)
{
    int e = blockIdx.x * 256 + threadIdx.x;
    if (e >= E) return;
    int b = e >> nsShift;
    int d = b * Nd + idx[e];
    int pos = offs[d] + atomicAdd(&cursor[d], 1);
    elist[pos] = e;
}

// ---------------------------------------------------------------------------
// FUSED gather + LayerNorm: dv[row] accumulated in registers, then
// v_out[row] = LN(v_in[row] + gate*dv) * gamma + beta written directly.
// Also: ds[row] = sum c[e]; cursor[row] = 0 for next transition.
// v_out must not alias src_val (host ping-pongs buffers for prop transitions).
// ---------------------------------------------------------------------------
#define ECHUNK 512
__launch_bounds__(256)
__global__ void gather_ln_kernel(const float* __restrict__ src_val, const float* __restrict__ c,
                                 const int* __restrict__ elist, const int* __restrict__ offs,
                                 const float* __restrict__ v_in, float* __restrict__ v_out,
                                 float* __restrict__ ds, int* __restrict__ cursor,
                                 const float* __restrict__ gamma, const float* __restrict__ beta,
                                 const float* __restrict__ gatePtr, int gateIdx, int nsShift)
{
    __shared__ float sc[ECHUNK];
    __shared__ int   srow[ECHUNK];
    __shared__ float part[4][512];
    __shared__ float pcs[4];
    __shared__ float red[4];
    long row = blockIdx.x;
    int t = threadIdx.x, w = t >> 6, lane = t & 63;
    int e0 = offs[row], e1 = offs[row + 1];
    int mask = (1 << nsShift) - 1;
    int cb = lane * 8;
    float a[8] = {};
    float cs = 0.f;
    float gate = 1.f;
    if (gatePtr) gate = 1.f / (1.f + expf(-gatePtr[gateIdx]));

    for (int cstart = e0; cstart < e1; cstart += ECHUNK) {
        int cnt = min(e1 - cstart, ECHUNK);
        for (int i = t; i < cnt; i += 256) {
            int e = elist[cstart + i];
            sc[i] = c[e];
            int b = e >> nsShift;
            int s = (e & mask) >> 4;
            srow[i] = (b << (nsShift - 4)) + s;
        }
        __syncthreads();
        int j = w;
        for (; j + 12 < cnt; j += 16) {
            float c0 = sc[j], c1 = sc[j + 4], c2 = sc[j + 8], c3 = sc[j + 12];
            const float* p0 = src_val + ((long)srow[j]      << 9) + cb;
            const float* p1 = src_val + ((long)srow[j + 4]  << 9) + cb;
            const float* p2 = src_val + ((long)srow[j + 8]  << 9) + cb;
            const float* p3 = src_val + ((long)srow[j + 12] << 9) + cb;
            float4 x00 = *(const float4*)p0,       x01 = *(const float4*)(p0 + 4);
            float4 x10 = *(const float4*)p1,       x11 = *(const float4*)(p1 + 4);
            float4 x20 = *(const float4*)p2,       x21 = *(const float4*)(p2 + 4);
            float4 x30 = *(const float4*)p3,       x31 = *(const float4*)(p3 + 4);
            a[0] += c0 * x00.x + c1 * x10.x + c2 * x20.x + c3 * x30.x;
            a[1] += c0 * x00.y + c1 * x10.y + c2 * x20.y + c3 * x30.y;
            a[2] += c0 * x00.z + c1 * x10.z + c2 * x20.z + c3 * x30.z;
            a[3] += c0 * x00.w + c1 * x10.w + c2 * x20.w + c3 * x30.w;
            a[4] += c0 * x01.x + c1 * x11.x + c2 * x21.x + c3 * x31.x;
            a[5] += c0 * x01.y + c1 * x11.y + c2 * x21.y + c3 * x31.y;
            a[6] += c0 * x01.z + c1 * x11.z + c2 * x21.z + c3 * x31.z;
            a[7] += c0 * x01.w + c1 * x11.w + c2 * x21.w + c3 * x31.w;
            cs += c0 + c1 + c2 + c3;
        }
        for (; j < cnt; j += 4) {
            float cv = sc[j];
            const float* p = src_val + ((long)srow[j] << 9) + cb;
            float4 x0 = *(const float4*)p, x1 = *(const float4*)(p + 4);
            a[0] += cv * x0.x; a[1] += cv * x0.y; a[2] += cv * x0.z; a[3] += cv * x0.w;
            a[4] += cv * x1.x; a[5] += cv * x1.y; a[6] += cv * x1.z; a[7] += cv * x1.w;
            cs += cv;
        }
        __syncthreads();
    }
#pragma unroll
    for (int i = 0; i < 8; ++i) part[w][cb + i] = a[i];
    if (lane == 0) pcs[w] = cs;
    __syncthreads();
    float r0 = part[0][t] + part[1][t] + part[2][t] + part[3][t];
    float r1 = part[0][t + 256] + part[1][t + 256] + part[2][t + 256] + part[3][t + 256];
    if (t == 0) { ds[row] = pcs[0] + pcs[1] + pcs[2] + pcs[3]; cursor[row] = 0; }

    // ---- LayerNorm on x = v_in + gate*dv ----
    const float* vi = v_in + (row << 9);
    float x0 = vi[t]       + gate * r0;
    float x1 = vi[t + 256] + gate * r1;
    float s = x0 + x1;
    for (int off = 32; off; off >>= 1) s += __shfl_down(s, off);
    if ((t & 63) == 0) red[t >> 6] = s;
    __syncthreads();
    float mean = (red[0] + red[1] + red[2] + red[3]) * (1.f / 512.f);
    float d0 = x0 - mean, d1 = x1 - mean;
    float ss = d0 * d0 + d1 * d1;
    for (int off = 32; off; off >>= 1) ss += __shfl_down(ss, off);
    __syncthreads();
    if ((t & 63) == 0) red[t >> 6] = ss;
    __syncthreads();
    float var = (red[0] + red[1] + red[2] + red[3]) * (1.f / 512.f);
    float rstd = rsqrtf(var + 1e-5f);
    float* vo = v_out + (row << 9);
    vo[t]       = d0 * rstd * gamma[t]       + beta[t];
    vo[t + 256] = d1 * rstd * gamma[t + 256] + beta[t + 256];
}

// ---------------------------------------------------------------------------
// state' = sign(x)*softmax(|x|), x = s + gate*ds. One block per batch.
// ---------------------------------------------------------------------------
__launch_bounds__(256)
__global__ void apply_state_kernel(const float* __restrict__ s_in, const float* __restrict__ ds,
                                   float* __restrict__ s_out, int Nd,
                                   const float* __restrict__ gatePtr, int gateIdx)
{
    __shared__ float sh[1024];
    __shared__ float red[4];
    int b = blockIdx.x, t = threadIdx.x;
    float gate = 1.f;
    if (gatePtr) gate = 1.f / (1.f + expf(-gatePtr[gateIdx]));
    float lmax = 0.f;
    for (int i = t; i < Nd; i += 256) {
        float x = s_in[b * Nd + i] + gate * ds[b * Nd + i];
        sh[i] = x;
        lmax = fmaxf(lmax, fabsf(x));
    }
    for (int off = 32; off; off >>= 1) lmax = fmaxf(lmax, __shfl_down(lmax, off));
    if ((t & 63) == 0) red[t >> 6] = lmax;
    __syncthreads();
    float bmax = fmaxf(fmaxf(red[0], red[1]), fmaxf(red[2], red[3]));
    float lsum = 0.f;
    for (int i = t; i < Nd; i += 256) lsum += expf(fabsf(sh[i]) - bmax);
    for (int off = 32; off; off >>= 1) lsum += __shfl_down(lsum, off);
    __syncthreads();
    if ((t & 63) == 0) red[t >> 6] = lsum;
    __syncthreads();
    float inv = 1.f / (red[0] + red[1] + red[2] + red[3]);
    for (int i = t; i < Nd; i += 256) {
        float x = sh[i];
        float sgn = (x > 0.f) ? 1.f : ((x < 0.f) ? -1.f : 0.f);
        s_out[b * Nd + i] = sgn * expf(fabsf(x) - bmax) * inv;
    }
}

// ---------------------------------------------------------------------------
// Plain softmax over rows, in place (read phase).
// ---------------------------------------------------------------------------
__launch_bounds__(256)
__global__ void softmax_rows_kernel(float* __restrict__ logits, int Nd)
{
    __shared__ float red[4];
    long row = blockIdx.x;
    int t = threadIdx.x;
    float* L = logits + row * (long)Nd;
    float lmax = -INFINITY;
    for (int i = t; i < Nd; i += 256) lmax = fmaxf(lmax, L[i]);
    for (int off = 32; off; off >>= 1) lmax = fmaxf(lmax, __shfl_down(lmax, off));
    if ((t & 63) == 0) red[t >> 6] = lmax;
    __syncthreads();
    float bmax = fmaxf(fmaxf(red[0], red[1]), fmaxf(red[2], red[3]));
    float lsum = 0.f;
    for (int i = t; i < Nd; i += 256) lsum += expf(L[i] - bmax);
    for (int off = 32; off; off >>= 1) lsum += __shfl_down(lsum, off);
    __syncthreads();
    if ((t & 63) == 0) red[t >> 6] = lsum;
    __syncthreads();
    float inv = 1.f / (red[0] + red[1] + red[2] + red[3]);
    for (int i = t; i < Nd; i += 256) L[i] = expf(L[i] - bmax) * inv;
}

// ---------------------------------------------------------------------------
extern "C" void kernel_launch(void* const* d_in, const int* in_sizes, int n_in,
                              void* d_out, int out_size, void* d_ws, size_t ws_size,
                              hipStream_t stream)
{
    const int Bn = 4, T = 1024, D = 512, R = 64;
    const int S0 = 1024, S1 = 256, S2 = 64;
    const long RT = (long)D * R;

    const float* tok_val    = (const float*)d_in[0];
    const float* tok_state  = (const float*)d_in[1];
    const float* mem_state0 = (const float*)d_in[2];
    const float* mem_val0   = (const float*)d_in[3];
    const float* mem_state1 = (const float*)d_in[4];
    const float* mem_val1   = (const float*)d_in[5];
    const float* mem_state2 = (const float*)d_in[6];
    const float* mem_val2   = (const float*)d_in[7];
    const float* write_route= (const float*)d_in[8];
    const float* prop_route = (const float*)d_in[9];
    const float* level_route= (const float*)d_in[10];
    const float* skip_route = (const float*)d_in[11];
    const float* skip_gates = (const float*)d_in[12];
    const float* ln_gamma   = (const float*)d_in[13];
    const float* ln_beta    = (const float*)d_in[14];
    const float* read_route = (const float*)d_in[15];
    const float* read_proj  = (const float*)d_in[16];
    const float* read_gates = (const float*)d_in[17];
    float* out = (float*)d_out;

    // workspace carve
    float* p = (float*)d_ws;
    float* v0  = p; p += (long)Bn * S0 * D;
    float* v0b = p; p += (long)Bn * S0 * D;
    float* s0  = p; p += Bn * S0;
    float* v1  = p; p += (long)Bn * S1 * D;
    float* v1b = p; p += (long)Bn * S1 * D;
    float* s1  = p; p += Bn * S1;
    float* v2  = p; p += (long)Bn * S2 * D;
    float* v2b = p; p += (long)Bn * S2 * D;
    float* s2  = p; p += Bn * S2;
    float* qb  = p; p += (long)Bn * T * R;
    float* kb  = p; p += (long)Bn * S0 * R;
    float* lb  = p; p += (long)Bn * T * S0;
    float* cbuf= p; p += (long)Bn * T * 16;
    int*   ib  = (int*)p; p += (long)Bn * T * 16;
    float* dsb = p; p += Bn * S0;
    float* rb  = p; p += (long)Bn * T * D;
    int* cntb  = (int*)p; p += Bn * S0;
    int* curb  = (int*)p; p += Bn * S0;
    int* offsb = (int*)p; p += Bn * S0 + 1;
    int* elistb= (int*)p; p += (long)Bn * T * 16;
    unsigned short* projT = (unsigned short*)p; p += (3 * (long)D * D) / 2 + 4;
    unsigned short* mvT   = (unsigned short*)p; p += ((long)Bn * D * S0) / 2 + 4;
    float* partb = p; p += 8L * Bn * (T + S0) * R;   // split-K partials

    auto proj = [&](const float* Aq, const float* Ak, const float* Wq, const float* Wk,
                    int Mq, int Mk, long sAq, long sAk, float* qout, float* kout) {
        proj_splitk_kernel<<<dim3((Mq + Mk) / 64, 8, Bn), 256, 0, stream>>>(
            Aq, Ak, Wq, Wk, partb, Mq, Mk, sAq, sAk, Bn);
        int total4 = Bn * (Mq + Mk) * 16;
        proj_reduce_kernel<<<(total4 + 255) / 256, 256, 0, stream>>>(
            partb, qout, kout, Mq, Mk, Bn);
    };

    // one-time zero of cnt + cursor (workspace is re-poisoned before every call)
    hipMemsetAsync(cntb, 0, (size_t)2 * Bn * S0 * sizeof(int), stream);

    auto trans = [&](const float* sv, const float* ss, const float* dval,
                     const float* W, int Ns, int Nd,
                     const float* v_in, float* v_out, const float* sin, float* sout,
                     int lvl, const float* gptr, int gidx) {
        proj(sv, dval, W, W + RT, Ns, Nd, (long)Ns * D, (long)Nd * D, qb, kb);
        gemm_f32_nt_kernel<<<dim3(Ns / 64, Nd / 64, Bn), 256, 0, stream>>>(
            qb, kb, lb, Ns, Nd, R, (long)Ns * R, (long)Nd * R, (long)Ns * Nd, 0.125f);
        int nsLog = 31 - __builtin_clz((unsigned)Ns);
        int nsShift = nsLog + 4;
        int rowBlocks = Bn * Ns / 4;
        if (Nd == 1024)
            topk_coeff_kernel<16><<<rowBlocks, 256, 0, stream>>>(lb, ss, ib, cbuf, cntb, nsLog, Nd);
        else if (Nd == 256)
            topk_coeff_kernel<4><<<rowBlocks, 256, 0, stream>>>(lb, ss, ib, cbuf, cntb, nsLog, Nd);
        else
            topk_coeff_kernel<1><<<rowBlocks, 256, 0, stream>>>(lb, ss, ib, cbuf, cntb, nsLog, Nd);
        int E = Bn * Ns * 16;
        scan_kernel<<<1, 256, 0, stream>>>(cntb, offsb, Bn * Nd);
        fill_edges_kernel<<<(E + 255) / 256, 256, 0, stream>>>(ib, offsb, curb, elistb,
                                                               nsShift, Nd, E);
        gather_ln_kernel<<<Bn * Nd, 256, 0, stream>>>(sv, cbuf, elistb, offsb,
                                                      v_in, v_out, dsb, curb,
                                                      ln_gamma + lvl * D, ln_beta + lvl * D,
                                                      gptr, gidx, nsShift);
        apply_state_kernel<<<Bn, 256, 0, stream>>>(sin, dsb, sout, Nd, gptr, gidx);
    };

    // ---- level 0 ----
    trans(tok_val, tok_state, mem_val0, write_route, T, S0,
          mem_val0, v0, mem_state0, s0, 0, nullptr, 0);
    trans(v0, s0, v0, prop_route + 0 * 2 * RT, S0, S0,
          v0, v0b, s0, s0, 0, nullptr, 0);                    // ping-pong: out = v0b

    // ---- level 1 ----
    trans(v0b, s0, mem_val1, level_route + 0 * 2 * RT, S0, S1,
          mem_val1, v1, mem_state1, s1, 1, nullptr, 0);
    trans(tok_val, tok_state, v1, skip_route + 0 * 2 * RT, T, S1,
          v1, v1, s1, s1, 1, skip_gates, 0);                  // in-place ok (sv=tok_val)
    trans(v1, s1, v1, prop_route + 1 * 2 * RT, S1, S1,
          v1, v1b, s1, s1, 1, nullptr, 0);                    // out = v1b

    // ---- level 2 ----
    trans(v1b, s1, mem_val2, level_route + 1 * 2 * RT, S1, S2,
          mem_val2, v2, mem_state2, s2, 2, nullptr, 0);
    trans(v0b, s0, v2, skip_route + 1 * 2 * RT, S0, S2,
          v2, v2, s2, s2, 2, skip_gates, 1);                  // in-place ok (sv=v0b)
    trans(v2, s2, v2, prop_route + 2 * 2 * RT, S2, S2,
          v2, v2b, s2, s2, 2, nullptr, 0);                    // out = v2b

    // ---- read phase ----
    transpose_bf16_kernel<<<dim3(D / 32, D / 32, 3), dim3(32, 8), 0, stream>>>(
        read_proj, projT, D, D, (long)D * D, (long)D * D);
    const float* mvs[3] = { v0b, v1b, v2b };
    const int nds[3] = { S0, S1, S2 };
    for (int l = 0; l < 3; ++l) {
        const float* mv = mvs[l];
        int Nd = nds[l];
        proj(tok_val, mv, read_route + (long)l * 2 * RT, read_route + (long)l * 2 * RT + RT,
             T, Nd, (long)T * D, (long)Nd * D, qb, kb);
        gemm_f32_nt_kernel<<<dim3(T / 64, Nd / 64, Bn), 256, 0, stream>>>(
            qb, kb, lb, T, Nd, R, (long)T * R, (long)Nd * R, (long)T * Nd, 0.125f);
        softmax_rows_kernel<<<Bn * T, 256, 0, stream>>>(lb, Nd);
        transpose_bf16_kernel<<<dim3(D / 32, Nd / 32, Bn), dim3(32, 8), 0, stream>>>(
            mv, mvT, Nd, D, (long)Nd * D, (long)D * Nd);
        gemm_mfma_kernel<<<dim3(T / 64, D / 64, Bn), 256, 0, stream>>>(
            lb, mvT, rb, T, D, Nd, (long)T * Nd, (long)D * Nd, (long)T * D,
            1.f, nullptr, 0, 0.f, nullptr);
        // out = (l==0 ? tok_val : out) + sigmoid(gate_l) * r x proj_l
        gemm_mfma_kernel<<<dim3(T / 64, D / 64, Bn), 256, 0, stream>>>(
            rb, projT + (long)l * D * D, out, T, D, D,
            (long)T * D, 0, (long)T * D, 1.f, read_gates, l,
            1.f, (l == 0) ? tok_val : nullptr);
    }
}